// Round 15
// baseline (261.563 us; speedup 1.0000x reference)
//
#include <hip/hip_runtime.h>

#define S_LEN 2048
#define NH 16
#define HD 64
#define DMODEL 1024
#define NTOK 4096
#define ELTS_PER 4194304  // B*S*D = NTOK*DMODEL
#define QSCALE 0.18033688f  // 0.125 * log2(e), folded into Q/Qb projections

typedef __attribute__((ext_vector_type(8))) __bf16 bfrag;
typedef __attribute__((ext_vector_type(8))) short s8v;
typedef __attribute__((ext_vector_type(4))) float f32x4;

__device__ inline float bf2f(short s) {
  unsigned int u = ((unsigned int)(unsigned short)s) << 16;
  float f;
  __builtin_memcpy(&f, &u, 4);
  return f;
}
__device__ inline short f2bf(float f) {
  unsigned int u;
  __builtin_memcpy(&u, &f, 4);
  u = (u + 0x7fffu + ((u >> 16) & 1u)) >> 16;
  return (short)u;
}
__device__ inline short f2bf_n(float f) {  // native convert (packed cvt)
  __bf16 h = (__bf16)f;
  short s;
  __builtin_memcpy(&s, &h, 2);
  return s;
}
__device__ inline float bflo(unsigned int u) {
  unsigned int t = u << 16;
  float f; __builtin_memcpy(&f, &t, 4); return f;
}
__device__ inline float bfhi(unsigned int u) {
  unsigned int t = u & 0xffff0000u;
  float f; __builtin_memcpy(&f, &t, 4); return f;
}
// async global -> LDS, 16B per lane (dest = wave-uniform base + lane*16)
__device__ __forceinline__ void gll16(const short* g, short* l) {
  __builtin_amdgcn_global_load_lds(
      (const __attribute__((address_space(1))) void*)g,
      (__attribute__((address_space(3))) void*)l, 16, 0, 0);
}

// ---------------- convert x: f32 -> bf16 ----------------
__global__ __launch_bounds__(256) void cvt_bf16_kernel(const float* __restrict__ in,
                                                       short* __restrict__ out, int n) {
  int i = (blockIdx.x * 256 + threadIdx.x) * 4;
  if (i + 3 < n) {
    float4 v = *reinterpret_cast<const float4*>(in + i);
    short4 o;
    o.x = f2bf(v.x); o.y = f2bf(v.y); o.z = f2bf(v.z); o.w = f2bf(v.w);
    *reinterpret_cast<short4*>(out + i) = o;
  }
}

// ---------- transpose + convert ALL weights: f32 [K][N=1024] -> bf16 [N][K] ----------
__global__ void transpose_cvt_all(const float* __restrict__ s0, const float* __restrict__ s1,
                                  const float* __restrict__ s2, const float* __restrict__ s3,
                                  const float* __restrict__ s4, const float* __restrict__ s5,
                                  const float* __restrict__ s6, const float* __restrict__ s7,
                                  short* d0, short* d1, short* d2, short* d3,
                                  short* d4, short* d5, short* d6, short* d7) {
  const int z = blockIdx.z;
  const int K = (z == 7) ? 2048 : 1024;
  if (blockIdx.y * 32 >= K) return;
  const float* srcs[8] = {s0, s1, s2, s3, s4, s5, s6, s7};
  short* dsts[8] = {d0, d1, d2, d3, d4, d5, d6, d7};
  const float* in = srcs[z];
  short* out = dsts[z];
  __shared__ float tile[32][33];
  int nb = blockIdx.x * 32, kb = blockIdx.y * 32;
  int tx = threadIdx.x, ty = threadIdx.y;  // block (32,8)
  for (int j = 0; j < 32; j += 8)
    tile[ty + j][tx] = in[(size_t)(kb + ty + j) * 1024 + nb + tx];
  __syncthreads();
  for (int j = 0; j < 32; j += 8)
    out[(size_t)(nb + ty + j) * K + kb + tx] = f2bf(tile[tx][ty + j]);
}

// ---------------- QKV GEMM: BK=32, issue-ahead dbuf, ONE barrier/step ----------
// LDS[r][slot s] = global[r][s ^ ((r>>1)&3)] (verified round-6 involution).
// Epilogue: C tile staged in LDS [128][136] bf16 (transposed for V/Vb), 16B stores.
__global__ __launch_bounds__(256) void gemm_qkv_kernel(
    const short* __restrict__ A, int lda, int K,
    const short* __restrict__ B0, const short* __restrict__ B1, const short* __restrict__ B2,
    const short* __restrict__ B3, const short* __restrict__ B4, const short* __restrict__ B5,
    const float* __restrict__ bias0, const float* __restrict__ bias1,
    const float* __restrict__ bias2, const float* __restrict__ bias3,
    const float* __restrict__ bias4, const float* __restrict__ bias5,
    short* __restrict__ outQ) {
  __shared__ short lds[128 * 136];  // 34.8 KB; K-loop uses first 32 KB (4 x 4096 shorts)
  const int tid = threadIdx.x;
  const int n0 = blockIdx.x * 128;
  const int m0 = blockIdx.y * 128;
  const short* Bp[6] = {B0, B1, B2, B3, B4, B5};
  const float* biasP[6] = {bias0, bias1, bias2, bias3, bias4, bias5};
  const int nsel = n0 >> 10;
  const int nc0 = n0 & 1023;
  const short* Bt = Bp[nsel] + (size_t)nc0 * K;
  const float* bsel = biasP[nsel];

  const int lane = tid & 63;
  const int w = tid >> 6;
  const int wm = (w >> 1) * 64;
  const int wn = (w & 1) * 64;
  const int lr = lane & 15;
  const int lg = lane >> 4;
  const int gr = lane >> 2;                             // staging row in 16-row group
  const int gs = (((lane & 3) ^ ((gr >> 1) & 3)) * 8);  // pre-swizzled source col
  const int rsw = (lr >> 1) & 3;                        // read-side swizzle

  f32x4 acc[4][4];
  for (int a = 0; a < 4; ++a)
    for (int b = 0; b < 4; ++b) acc[a][b] = {0.f, 0.f, 0.f, 0.f};

#define QKV_STAGE(K0, AD, BD)                                              \
  do {                                                                     \
    const short* Ag = A + (size_t)(m0 + w * 32 + gr) * lda + (K0) + gs;    \
    gll16(Ag, (AD) + (w * 32) * 32);                                       \
    gll16(Ag + (size_t)16 * lda, (AD) + (w * 32 + 16) * 32);               \
    const short* Bg = Bt + (size_t)(w * 32 + gr) * K + (K0) + gs;          \
    gll16(Bg, (BD) + (w * 32) * 32);                                       \
    gll16(Bg + (size_t)16 * K, (BD) + (w * 32 + 16) * 32);                 \
  } while (0)

  QKV_STAGE(0, lds, lds + 8192);
  __syncthreads();
  for (int k0 = 0; k0 < K; k0 += 32) {
    const int cur = (k0 >> 5) & 1;
    if (k0 + 32 < K)
      QKV_STAGE(k0 + 32, lds + (cur ^ 1) * 4096, lds + 8192 + (cur ^ 1) * 4096);
    const short* As = lds + cur * 4096;
    const short* Bs = lds + 8192 + cur * 4096;
    bfrag af[4], bf[4];
    for (int t = 0; t < 4; ++t) {
      af[t] = *reinterpret_cast<const bfrag*>(&As[(wm + t * 16 + lr) * 32 + ((lg ^ rsw) * 8)]);
      bf[t] = *reinterpret_cast<const bfrag*>(&Bs[(wn + t * 16 + lr) * 32 + ((lg ^ rsw) * 8)]);
    }
    for (int mt = 0; mt < 4; ++mt)
      for (int nt = 0; nt < 4; ++nt)
        acc[mt][nt] = __builtin_amdgcn_mfma_f32_16x16x32_bf16(af[mt], bf[nt], acc[mt][nt], 0, 0, 0);
    __syncthreads();  // drains gll16 (issued early) + protects buffer reuse
  }
#undef QKV_STAGE

  const float cmul = (nsel == 0 || nsel == 3) ? QSCALE : 1.0f;
  const bool tr = (nsel == 2 || nsel == 5);
  for (int mt = 0; mt < 4; ++mt)
    for (int nt = 0; nt < 4; ++nt) {
      int c = wn + nt * 16 + lr;
      float bv = bsel[nc0 + c];
      for (int i = 0; i < 4; ++i) {
        int r = wm + mt * 16 + lg * 4 + i;
        short v16 = f2bf_n((acc[mt][nt][i] + bv) * cmul);
        if (tr) lds[c * 136 + r] = v16;
        else lds[r * 136 + c] = v16;
      }
    }
  __syncthreads();
  const int bb = m0 >> 11;
  const int sloc = m0 & 2047;
  const int hh0 = nc0 >> 6;
  short* basebuf = outQ + (size_t)nsel * ELTS_PER;
  for (int j = 0; j < 8; ++j) {
    int gid = j * 256 + tid;
    int rr = gid >> 4;
    int ch = gid & 15;
    s8v v = *reinterpret_cast<const s8v*>(&lds[rr * 136 + ch * 8]);
    if (tr) {
      int hh = hh0 + (rr >> 6), d = rr & 63;
      *reinterpret_cast<s8v*>(
          basebuf + ((size_t)(bb * NH + hh) * HD + d) * S_LEN + sloc + ch * 8) = v;
    } else {
      int hh = hh0 + (ch >> 3), d0 = (ch & 7) * 8;
      *reinterpret_cast<s8v*>(
          basebuf + ((size_t)(bb * NH + hh) * S_LEN + sloc + rr) * HD + d0) = v;
    }
  }
}

// ---------------- K-split GEMM (BK=32, issue-ahead dbuf), f32 partial outputs --------
__global__ __launch_bounds__(256) void gemm_ksplit_kernel(
    const short* __restrict__ A0, const short* __restrict__ A1, int lda,
    const short* __restrict__ B, int ldb, int K,
    const float* __restrict__ bias, float* __restrict__ out0, float* __restrict__ out1) {
  __shared__ short lds[16384];  // 32 KB
  const int tid = threadIdx.x;
  const int n0 = blockIdx.x * 128;
  const int m0 = blockIdx.y * 128;
  const int z = blockIdx.z;
  const short* A = z ? A1 : A0;
  const short* Bt = B + (size_t)n0 * ldb + z * K;
  float* outp = z ? out1 : out0;

  const int lane = tid & 63;
  const int w = tid >> 6;
  const int wm = (w >> 1) * 64;
  const int wn = (w & 1) * 64;
  const int lr = lane & 15;
  const int lg = lane >> 4;
  const int gr = lane >> 2;
  const int gs = (((lane & 3) ^ ((gr >> 1) & 3)) * 8);
  const int rsw = (lr >> 1) & 3;

  f32x4 acc[4][4];
  for (int a = 0; a < 4; ++a)
    for (int b = 0; b < 4; ++b) acc[a][b] = {0.f, 0.f, 0.f, 0.f};

#define KS_STAGE(K0, AD, BD)                                               \
  do {                                                                     \
    const short* Ag = A + (size_t)(m0 + w * 32 + gr) * lda + (K0) + gs;    \
    gll16(Ag, (AD) + (w * 32) * 32);                                       \
    gll16(Ag + (size_t)16 * lda, (AD) + (w * 32 + 16) * 32);               \
    const short* Bg = Bt + (size_t)(w * 32 + gr) * ldb + (K0) + gs;        \
    gll16(Bg, (BD) + (w * 32) * 32);                                       \
    gll16(Bg + (size_t)16 * ldb, (BD) + (w * 32 + 16) * 32);               \
  } while (0)

  KS_STAGE(0, lds, lds + 8192);
  __syncthreads();
  for (int k0 = 0; k0 < K; k0 += 32) {
    const int cur = (k0 >> 5) & 1;
    if (k0 + 32 < K)
      KS_STAGE(k0 + 32, lds + (cur ^ 1) * 4096, lds + 8192 + (cur ^ 1) * 4096);
    const short* As = lds + cur * 4096;
    const short* Bs = lds + 8192 + cur * 4096;
    bfrag af[4], bf[4];
    for (int t = 0; t < 4; ++t) {
      af[t] = *reinterpret_cast<const bfrag*>(&As[(wm + t * 16 + lr) * 32 + ((lg ^ rsw) * 8)]);
      bf[t] = *reinterpret_cast<const bfrag*>(&Bs[(wn + t * 16 + lr) * 32 + ((lg ^ rsw) * 8)]);
    }
    for (int mt = 0; mt < 4; ++mt)
      for (int nt = 0; nt < 4; ++nt)
        acc[mt][nt] = __builtin_amdgcn_mfma_f32_16x16x32_bf16(af[mt], bf[nt], acc[mt][nt], 0, 0, 0);
    __syncthreads();
  }
#undef KS_STAGE

  for (int mt = 0; mt < 4; ++mt)
    for (int nt = 0; nt < 4; ++nt)
      for (int i = 0; i < 4; ++i) {
        int row = m0 + wm + mt * 16 + lg * 4 + i;
        int col = n0 + wn + nt * 16 + lr;
        float v = acc[mt][nt][i] + (z == 0 ? bias[col] : 0.f);
        outp[(size_t)row * DMODEL + col] = v;
      }
}

// ---------------- causal flash attention fwd (v10: cooperative dbuf staging) ------
// Block = 128 contiguous q-rows (4 waves x 32, equal kt ranges 0..2j+1).
// Issue-ahead double-buffered K/V LDS tiles (one barrier per k-tile).
// CU pairing: slots t and t+8 -> j and 15-j => constant per-CU work.
__global__ __launch_bounds__(256) void attn_fwd_kernel(const short* __restrict__ Q,
                                                       const short* __restrict__ Kk,
                                                       const short* __restrict__ VT,
                                                       short* __restrict__ fwd) {
  __shared__ short Kls[2][64 * 64];
  __shared__ short Vls[2][64 * 64];
  __shared__ short Ps[4][32 * 72];
  const int tid = threadIdx.x;
  const int lane = tid & 63;
  const int w = tid >> 6;
  const int lr = lane & 15;
  const int lg = lane >> 4;
  const int f = blockIdx.x;              // 0..511
  const int xcd = f & 7;
  const int s = f >> 3;                  // 0..63
  const int bhl = s & 3;
  const int t = s >> 2;                  // 0..15
  const int j = (t < 8) ? t : (23 - t);  // pair (t, t+8) -> j + (15-j)
  const int bh = xcd * 4 + bhl;
  const int b = bh >> 4;
  const int h = bh & 15;
  const size_t hb = (size_t)bh * S_LEN * HD;
  short* Pw = Ps[w];

  s8v onesi = {0x3F80, 0x3F80, 0x3F80, 0x3F80, 0x3F80, 0x3F80, 0x3F80, 0x3F80};
  bfrag onesv;
  __builtin_memcpy(&onesv, &onesi, 16);

  const int q0 = j * 128 + w * 32;
  const int ktmax = 2 * j + 1;

  const int rl8 = lane >> 3;
  const int gch = (lane & 7) ^ rl8;

  bfrag qf[2][2];
  for (int mt = 0; mt < 2; ++mt)
    for (int kc = 0; kc < 2; ++kc)
      qf[mt][kc] = *reinterpret_cast<const bfrag*>(
          Q + hb + (size_t)(q0 + mt * 16 + lr) * HD + kc * 32 + lg * 8);

  f32x4 oacc[2][4];
  for (int mt = 0; mt < 2; ++mt)
    for (int nd = 0; nd < 4; ++nd) oacc[mt][nd] = {0.f, 0.f, 0.f, 0.f};
  f32x4 osum[2];
  osum[0] = {0.f, 0.f, 0.f, 0.f};
  osum[1] = {0.f, 0.f, 0.f, 0.f};

#define AF_STAGE(KT, BUF)                                                            \
  do {                                                                               \
    const short* Kg = Kk + hb + (size_t)((KT) * 64 + w * 16 + rl8) * HD + gch * 8;   \
    gll16(Kg, &Kls[BUF][(w * 16) * 64]);                                             \
    gll16(Kg + (size_t)8 * HD, &Kls[BUF][(w * 16 + 8) * 64]);                        \
    const short* Vg = VT + hb + (size_t)(w * 16 + rl8) * S_LEN + (KT) * 64 + gch * 8;\
    gll16(Vg, &Vls[BUF][(w * 16) * 64]);                                             \
    gll16(Vg + (size_t)8 * S_LEN, &Vls[BUF][(w * 16 + 8) * 64]);                     \
  } while (0)

  AF_STAGE(0, 0);
  __syncthreads();
  for (int kt = 0; kt <= ktmax; ++kt) {
    const int cur = kt & 1;
    if (kt < ktmax) {
      if (cur == 0) AF_STAGE(kt + 1, 1);
      else AF_STAGE(kt + 1, 0);
    }
    // QK^T from swizzled K LDS
    bfrag kf[4][2];
    for (int nb = 0; nb < 4; ++nb)
      for (int kc = 0; kc < 2; ++kc)
        kf[nb][kc] = *reinterpret_cast<const bfrag*>(
            &Kls[cur][(nb * 16 + lr) * 64 + (((kc * 4 + lg) ^ (lr & 7)) * 8)]);
    f32x4 sv[2][4];
    for (int mt = 0; mt < 2; ++mt)
      for (int nb = 0; nb < 4; ++nb) {
        f32x4 z = {0.f, 0.f, 0.f, 0.f};
        z = __builtin_amdgcn_mfma_f32_16x16x32_bf16(qf[mt][0], kf[nb][0], z, 0, 0, 0);
        sv[mt][nb] = __builtin_amdgcn_mfma_f32_16x16x32_bf16(qf[mt][1], kf[nb][1], z, 0, 0, 0);
      }
    if (kt * 64 + 63 > q0) {
      for (int mt = 0; mt < 2; ++mt)
        for (int nb = 0; nb < 4; ++nb)
          for (int i = 0; i < 4; ++i) {
            int colg = kt * 64 + nb * 16 + lr;
            int rowg = q0 + mt * 16 + lg * 4 + i;
            if (colg > rowg) sv[mt][nb][i] = -1e30f;
          }
    }
    for (int mt = 0; mt < 2; ++mt)
      for (int nb = 0; nb < 4; ++nb)
        for (int i = 0; i < 4; ++i)
          Pw[(mt * 16 + lg * 4 + i) * 72 + nb * 16 + lr] = f2bf_n(exp2f(sv[mt][nb][i]));
    bfrag vf[4][2];
    for (int nd = 0; nd < 4; ++nd)
      for (int kc = 0; kc < 2; ++kc)
        vf[nd][kc] = *reinterpret_cast<const bfrag*>(
            &Vls[cur][(nd * 16 + lr) * 64 + (((kc * 4 + lg) ^ (lr & 7)) * 8)]);
    for (int mt = 0; mt < 2; ++mt) {
      bfrag pa0 = *reinterpret_cast<const bfrag*>(&Pw[(mt * 16 + lr) * 72 + lg * 8]);
      bfrag pa1 = *reinterpret_cast<const bfrag*>(&Pw[(mt * 16 + lr) * 72 + 32 + lg * 8]);
      for (int nd = 0; nd < 4; ++nd) {
        oacc[mt][nd] = __builtin_amdgcn_mfma_f32_16x16x32_bf16(pa0, vf[nd][0], oacc[mt][nd], 0, 0, 0);
        oacc[mt][nd] = __builtin_amdgcn_mfma_f32_16x16x32_bf16(pa1, vf[nd][1], oacc[mt][nd], 0, 0, 0);
      }
      osum[mt] = __builtin_amdgcn_mfma_f32_16x16x32_bf16(pa0, onesv, osum[mt], 0, 0, 0);
      osum[mt] = __builtin_amdgcn_mfma_f32_16x16x32_bf16(pa1, onesv, osum[mt], 0, 0, 0);
    }
    __syncthreads();  // drains early-issued gll16 + protects buffer reuse
  }
#undef AF_STAGE

  for (int mt = 0; mt < 2; ++mt)
    for (int i = 0; i < 4; ++i) {
      int rowg = q0 + mt * 16 + lg * 4 + i;
      float inv = 1.0f / osum[mt][i];
      for (int nd = 0; nd < 4; ++nd)
        fwd[(size_t)(b * S_LEN + rowg) * DMODEL + h * HD + nd * 16 + lr] =
            f2bf(oacc[mt][nd][i] * inv);
    }
}

// ---------------- windowed backward attention (MFMA single-tile) ----------------
__global__ __launch_bounds__(256) void attn_bwd_kernel(const short* __restrict__ Qb,
                                                       const short* __restrict__ Kb,
                                                       const short* __restrict__ VT,
                                                       short* __restrict__ bwd) {
  __shared__ short Ps[4][32 * 72];
  const int tid = threadIdx.x;
  const int lane = tid & 63;
  const int w = tid >> 6;
  const int lr = lane & 15;
  const int lg = lane >> 4;
  const int h = blockIdx.y;
  const int b = blockIdx.z;
  const size_t hb = (size_t)(b * NH + h) * S_LEN * HD;
  const int q0 = blockIdx.x * 128 + w * 32;
  short* Pw = Ps[w];

  bfrag qf[2][2];
  for (int mt = 0; mt < 2; ++mt)
    for (int kc = 0; kc < 2; ++kc)
      qf[mt][kc] = *reinterpret_cast<const bfrag*>(
          Qb + hb + (size_t)(q0 + mt * 16 + lr) * HD + kc * 32 + lg * 8);
  bfrag kf[4][2];
  for (int nb = 0; nb < 4; ++nb) {
    int kr = q0 + nb * 16 + lr;
    kr = min(kr, S_LEN - 1);
    for (int kc = 0; kc < 2; ++kc)
      kf[nb][kc] = *reinterpret_cast<const bfrag*>(
          Kb + hb + (size_t)kr * HD + kc * 32 + lg * 8);
  }
  f32x4 sv[2][4];
  for (int mt = 0; mt < 2; ++mt)
    for (int nb = 0; nb < 4; ++nb) {
      f32x4 z = {0.f, 0.f, 0.f, 0.f};
      z = __builtin_amdgcn_mfma_f32_16x16x32_bf16(qf[mt][0], kf[nb][0], z, 0, 0, 0);
      sv[mt][nb] = __builtin_amdgcn_mfma_f32_16x16x32_bf16(qf[mt][1], kf[nb][1], z, 0, 0, 0);
    }
  float mx[2][4];
  for (int mt = 0; mt < 2; ++mt)
    for (int i = 0; i < 4; ++i) {
      int rowg = q0 + mt * 16 + lg * 4 + i;
      float m = -1e30f;
      for (int nb = 0; nb < 4; ++nb) {
        int colg = q0 + nb * 16 + lr;
        float t = sv[mt][nb][i];
        bool valid = (colg > rowg) && (colg <= rowg + 32) && (colg < S_LEN);
        if (!valid) t = -1e30f;
        sv[mt][nb][i] = t;
        m = fmaxf(m, t);
      }
      mx[mt][i] = m;
    }
  for (int off = 1; off < 16; off <<= 1)
    for (int mt = 0; mt < 2; ++mt)
      for (int i = 0; i < 4; ++i) mx[mt][i] = fmaxf(mx[mt][i], __shfl_xor(mx[mt][i], off));
  float rs[2][4] = {{0.f, 0.f, 0.f, 0.f}, {0.f, 0.f, 0.f, 0.f}};
  for (int mt = 0; mt < 2; ++mt)
    for (int nb = 0; nb < 4; ++nb)
      for (int i = 0; i < 4; ++i) {
        float p = exp2f(sv[mt][nb][i] - mx[mt][i]);
        rs[mt][i] += p;
        Pw[(mt * 16 + lg * 4 + i) * 72 + nb * 16 + lr] = f2bf_n(p);
      }
  for (int off = 1; off < 16; off <<= 1)
    for (int mt = 0; mt < 2; ++mt)
      for (int i = 0; i < 4; ++i) rs[mt][i] += __shfl_xor(rs[mt][i], off);
  bfrag vf[4][2];
  for (int nd = 0; nd < 4; ++nd)
    for (int kc = 0; kc < 2; ++kc) {
      int sbase = q0 + kc * 32 + lg * 8;
      sbase = min(sbase, S_LEN - 8);
      vf[nd][kc] = *reinterpret_cast<const bfrag*>(
          VT + hb + (size_t)(nd * 16 + lr) * S_LEN + sbase);
    }
  f32x4 oacc[2][4];
  for (int mt = 0; mt < 2; ++mt)
    for (int nd = 0; nd < 4; ++nd) oacc[mt][nd] = {0.f, 0.f, 0.f, 0.f};
  for (int mt = 0; mt < 2; ++mt) {
    bfrag pa0 = *reinterpret_cast<const bfrag*>(&Pw[(mt * 16 + lr) * 72 + lg * 8]);
    bfrag pa1 = *reinterpret_cast<const bfrag*>(&Pw[(mt * 16 + lr) * 72 + 32 + lg * 8]);
    for (int nd = 0; nd < 4; ++nd) {
      oacc[mt][nd] = __builtin_amdgcn_mfma_f32_16x16x32_bf16(pa0, vf[nd][0], oacc[mt][nd], 0, 0, 0);
      oacc[mt][nd] = __builtin_amdgcn_mfma_f32_16x16x32_bf16(pa1, vf[nd][1], oacc[mt][nd], 0, 0, 0);
    }
  }
  for (int mt = 0; mt < 2; ++mt)
    for (int nd = 0; nd < 4; ++nd)
      for (int i = 0; i < 4; ++i) {
        int rowg = q0 + mt * 16 + lg * 4 + i;
        float ov = oacc[mt][nd][i] / rs[mt][i];
        bwd[(size_t)(b * S_LEN + rowg) * DMODEL + h * HD + nd * 16 + lr] = f2bf(ov);
      }
}

// ---------------- row S-1 of bwd: uniform mean over all Vb keys ----------------
__global__ __launch_bounds__(256) void vmean_kernel(const short* __restrict__ VT,
                                                    short* __restrict__ bwd) {
  __shared__ float red[256];
  const int bh = blockIdx.x;  // b*NH + h
  const int d = threadIdx.x >> 2;
  const int seg = threadIdx.x & 3;
  const short* row = VT + (size_t)bh * S_LEN * HD + (size_t)d * S_LEN + seg * 512;
  float s = 0.f;
  for (int j = 0; j < 512; j += 8) {
    uint4 v = *reinterpret_cast<const uint4*>(row + j);
    s += bflo(v.x) + bfhi(v.x) + bflo(v.y) + bfhi(v.y) +
         bflo(v.z) + bfhi(v.z) + bflo(v.w) + bfhi(v.w);
  }
  red[threadIdx.x] = s;
  __syncthreads();
  if (seg == 0) {
    float t = red[d * 4] + red[d * 4 + 1] + red[d * 4 + 2] + red[d * 4 + 3];
    int b = bh >> 4, h = bh & 15;
    bwd[((size_t)(b * S_LEN + S_LEN - 1)) * DMODEL + h * HD + d] = f2bf(t * (1.f / S_LEN));
  }
}

// ---------------- gate LN + sigmoid + fuse (sums 2 partials) ----------------
__global__ __launch_bounds__(256) void ln_gate_fuse_kernel(
    const float* __restrict__ g0p, const float* __restrict__ g1p,
    const float* __restrict__ gln_g, const float* __restrict__ gln_b,
    const short* __restrict__ fwd, const short* __restrict__ bwd,
    const float* __restrict__ bstr, short* __restrict__ fused) {
  __shared__ float red[8];
  const int row = blockIdx.x;
  const int tid = threadIdx.x;
  const int lane = tid & 63;
  const int w = tid >> 6;
  float4 x0 = *reinterpret_cast<const float4*>(g0p + (size_t)row * DMODEL + tid * 4);
  float4 x1 = *reinterpret_cast<const float4*>(g1p + (size_t)row * DMODEL + tid * 4);
  float xa[4] = {x0.x + x1.x, x0.y + x1.y, x0.z + x1.z, x0.w + x1.w};
  float s = xa[0] + xa[1] + xa[2] + xa[3];
  float ss = xa[0] * xa[0] + xa[1] * xa[1] + xa[2] * xa[2] + xa[3] * xa[3];
  for (int off = 1; off < 64; off <<= 1) {
    s += __shfl_xor(s, off);
    ss += __shfl_xor(ss, off);
  }
  if (lane == 0) { red[w] = s; red[4 + w] = ss; }
  __syncthreads();
  s = red[0] + red[1] + red[2] + red[3];
  ss = red[4] + red[5] + red[6] + red[7];
  const float mean = s * (1.f / DMODEL);
  const float var = ss * (1.f / DMODEL) - mean * mean;
  const float rstd = rsqrtf(var + 1e-5f);
  const float strength = 0.3f / (1.f + __expf(-bstr[0]));
  for (int e = 0; e < 4; ++e) {
    int idx = tid * 4 + e;
    float g = (xa[e] - mean) * rstd * gln_g[idx] + gln_b[idx];
    float gate = 1.f / (1.f + __expf(-g));
    float f = bf2f(fwd[(size_t)row * DMODEL + idx]) +
              strength * gate * bf2f(bwd[(size_t)row * DMODEL + idx]);
    fused[(size_t)row * DMODEL + idx] = f2bf(f);
  }
}

// ---------------- final residual LN (sums 2 partials) ----------------
__global__ __launch_bounds__(256) void final_ln_kernel(const float* __restrict__ x,
                                                       const float* __restrict__ o0p,
                                                       const float* __restrict__ o1p,
                                                       const float* __restrict__ ln_g,
                                                       const float* __restrict__ ln_b,
                                                       float* __restrict__ y) {
  __shared__ float red[8];
  const int row = blockIdx.x;
  const int tid = threadIdx.x;
  const int lane = tid & 63;
  const int w = tid >> 6;
  float4 xv = *reinterpret_cast<const float4*>(x + (size_t)row * DMODEL + tid * 4);
  float4 o0 = *reinterpret_cast<const float4*>(o0p + (size_t)row * DMODEL + tid * 4);
  float4 o1 = *reinterpret_cast<const float4*>(o1p + (size_t)row * DMODEL + tid * 4);
  float t[4] = {xv.x + o0.x + o1.x, xv.y + o0.y + o1.y,
                xv.z + o0.z + o1.z, xv.w + o0.w + o1.w};
  float s = t[0] + t[1] + t[2] + t[3];
  float ss = t[0] * t[0] + t[1] * t[1] + t[2] * t[2] + t[3] * t[3];
  for (int off = 1; off < 64; off <<= 1) {
    s += __shfl_xor(s, off);
    ss += __shfl_xor(ss, off);
  }
  if (lane == 0) { red[w] = s; red[4 + w] = ss; }
  __syncthreads();
  s = red[0] + red[1] + red[2] + red[3];
  ss = red[4] + red[5] + red[6] + red[7];
  const float mean = s * (1.f / DMODEL);
  const float var = ss * (1.f / DMODEL) - mean * mean;
  const float rstd = rsqrtf(var + 1e-5f);
  for (int e = 0; e < 4; ++e) {
    int idx = tid * 4 + e;
    y[(size_t)row * DMODEL + idx] = (t[e] - mean) * rstd * ln_g[idx] + ln_b[idx];
  }
}

extern "C" void kernel_launch(void* const* d_in, const int* in_sizes, int n_in,
                              void* d_out, int out_size, void* d_ws, size_t ws_size,
                              hipStream_t stream) {
  const float* x = (const float*)d_in[0];
  const float* fq_w = (const float*)d_in[1];
  const float* fq_b = (const float*)d_in[2];
  const float* fk_w = (const float*)d_in[3];
  const float* fk_b = (const float*)d_in[4];
  const float* fv_w = (const float*)d_in[5];
  const float* fv_b = (const float*)d_in[6];
  const float* bq_w = (const float*)d_in[7];
  const float* bq_b = (const float*)d_in[8];
  const float* bk_w = (const float*)d_in[9];
  const float* bk_b = (const float*)d_in[10];
  const float* bv_w = (const float*)d_in[11];
  const float* bv_b = (const float*)d_in[12];
  const float* gate_w = (const float*)d_in[13];
  const float* gate_b = (const float*)d_in[14];
  const float* gln_g = (const float*)d_in[15];
  const float* gln_b = (const float*)d_in[16];
  const float* bstr = (const float*)d_in[17];
  const float* out_w = (const float*)d_in[18];
  const float* out_b = (const float*)d_in[19];
  const float* ln_g = (const float*)d_in[20];
  const float* ln_b = (const float*)d_in[21];

  char* ws = (char*)d_ws;
  const size_t MB = 1u << 20;
  short* xb = (short*)(ws + 0);
  short* wT0 = (short*)(ws + 8 * MB);
  short* wT1 = (short*)(ws + 10 * MB);
  short* wT2 = (short*)(ws + 12 * MB);
  short* wT3 = (short*)(ws + 14 * MB);
  short* wT4 = (short*)(ws + 16 * MB);
  short* wT5 = (short*)(ws + 18 * MB);
  short* gwT = (short*)(ws + 20 * MB);
  short* owT = (short*)(ws + 24 * MB);
  short* qkv = (short*)(ws + 26 * MB);
  short* fwd = (short*)(ws + 0);
  short* bwdb = (short*)(ws + 8 * MB);
  float* G0 = (float*)(ws + 26 * MB);
  float* G1 = (float*)(ws + 42 * MB);
  short* fused = (short*)(ws + 58 * MB);
  float* O0 = (float*)(ws + 26 * MB);
  float* O1 = (float*)(ws + 42 * MB);

  cvt_bf16_kernel<<<4096, 256, 0, stream>>>(x, xb, ELTS_PER);
  transpose_cvt_all<<<dim3(32, 64, 8), dim3(32, 8), 0, stream>>>(
      fq_w, fk_w, fv_w, bq_w, bk_w, bv_w, out_w, gate_w,
      wT0, wT1, wT2, wT3, wT4, wT5, owT, gwT);

  gemm_qkv_kernel<<<dim3(48, 32), 256, 0, stream>>>(
      xb, 1024, 1024, wT0, wT1, wT2, wT3, wT4, wT5,
      fq_b, fk_b, fv_b, bq_b, bk_b, bv_b, qkv);

  attn_fwd_kernel<<<512, 256, 0, stream>>>(
      qkv, qkv + (size_t)ELTS_PER, qkv + 2 * (size_t)ELTS_PER, fwd);
  attn_bwd_kernel<<<dim3(16, 16, 2), 256, 0, stream>>>(
      qkv + 3 * (size_t)ELTS_PER, qkv + 4 * (size_t)ELTS_PER, qkv + 5 * (size_t)ELTS_PER, bwdb);
  vmean_kernel<<<32, 256, 0, stream>>>(qkv + 5 * (size_t)ELTS_PER, bwdb);

  gemm_ksplit_kernel<<<dim3(8, 32, 2), 256, 0, stream>>>(
      fwd, bwdb, 1024, gwT, 2048, 1024, gate_b, G0, G1);

  ln_gate_fuse_kernel<<<4096, 256, 0, stream>>>(G0, G1, gln_g, gln_b, fwd, bwdb, bstr, fused);

  gemm_ksplit_kernel<<<dim3(8, 32, 2), 256, 0, stream>>>(
      fused, fused + 512, 1024, owT, 1024, 512, out_b, O0, O1);

  final_ln_kernel<<<4096, 256, 0, stream>>>(x, O0, O1, ln_g, ln_b, (float*)d_out);
}

// Round 16
// 247.346 us; speedup vs baseline: 1.0575x; 1.0575x over previous
//
#include <hip/hip_runtime.h>

#define S_LEN 2048
#define NH 16
#define HD 64
#define DMODEL 1024
#define NTOK 4096
#define ELTS_PER 4194304  // B*S*D = NTOK*DMODEL
#define QSCALE 0.18033688f  // 0.125 * log2(e), folded into Q/Qb projections

typedef __attribute__((ext_vector_type(8))) __bf16 bfrag;
typedef __attribute__((ext_vector_type(8))) short s8v;
typedef __attribute__((ext_vector_type(4))) float f32x4;

__device__ inline float bf2f(short s) {
  unsigned int u = ((unsigned int)(unsigned short)s) << 16;
  float f;
  __builtin_memcpy(&f, &u, 4);
  return f;
}
__device__ inline short f2bf(float f) {
  unsigned int u;
  __builtin_memcpy(&u, &f, 4);
  u = (u + 0x7fffu + ((u >> 16) & 1u)) >> 16;
  return (short)u;
}
__device__ inline short f2bf_n(float f) {  // native convert (packed cvt)
  __bf16 h = (__bf16)f;
  short s;
  __builtin_memcpy(&s, &h, 2);
  return s;
}
__device__ inline float bflo(unsigned int u) {
  unsigned int t = u << 16;
  float f; __builtin_memcpy(&f, &t, 4); return f;
}
__device__ inline float bfhi(unsigned int u) {
  unsigned int t = u & 0xffff0000u;
  float f; __builtin_memcpy(&f, &t, 4); return f;
}
// async global -> LDS, 16B per lane (dest = wave-uniform base + lane*16)
__device__ __forceinline__ void gll16(const short* g, short* l) {
  __builtin_amdgcn_global_load_lds(
      (const __attribute__((address_space(1))) void*)g,
      (__attribute__((address_space(3))) void*)l, 16, 0, 0);
}

// ---- prep: z<8 -> transpose+convert weights f32 [K][1024] -> bf16 [1024][K];
//      z==8 -> convert x f32 -> bf16 (8 elems/thread) ----
__global__ void prep_kernel(const float* __restrict__ s0, const float* __restrict__ s1,
                            const float* __restrict__ s2, const float* __restrict__ s3,
                            const float* __restrict__ s4, const float* __restrict__ s5,
                            const float* __restrict__ s6, const float* __restrict__ s7,
                            short* d0, short* d1, short* d2, short* d3,
                            short* d4, short* d5, short* d6, short* d7,
                            const float* __restrict__ xin, short* __restrict__ xout) {
  const int z = blockIdx.z;
  if (z == 8) {
    int bid = blockIdx.y * 32 + blockIdx.x;                 // 0..2047
    int t256 = threadIdx.y * 32 + threadIdx.x;
    int i = (bid * 256 + t256) * 8;
    float4 v0 = *reinterpret_cast<const float4*>(xin + i);
    float4 v1 = *reinterpret_cast<const float4*>(xin + i + 4);
    short o[8] = {f2bf(v0.x), f2bf(v0.y), f2bf(v0.z), f2bf(v0.w),
                  f2bf(v1.x), f2bf(v1.y), f2bf(v1.z), f2bf(v1.w)};
    s8v ov;
    __builtin_memcpy(&ov, o, 16);
    *reinterpret_cast<s8v*>(xout + i) = ov;
    return;
  }
  const int K = (z == 7) ? 2048 : 1024;
  if (blockIdx.y * 32 >= K) return;
  const float* srcs[8] = {s0, s1, s2, s3, s4, s5, s6, s7};
  short* dsts[8] = {d0, d1, d2, d3, d4, d5, d6, d7};
  const float* in = srcs[z];
  short* out = dsts[z];
  __shared__ float tile[32][33];
  int nb = blockIdx.x * 32, kb = blockIdx.y * 32;
  int tx = threadIdx.x, ty = threadIdx.y;  // block (32,8)
  for (int j = 0; j < 32; j += 8)
    tile[ty + j][tx] = in[(size_t)(kb + ty + j) * 1024 + nb + tx];
  __syncthreads();
  for (int j = 0; j < 32; j += 8)
    out[(size_t)(nb + ty + j) * K + kb + tx] = f2bf(tile[tx][ty + j]);
}

// ---------------- QKV GEMM: BK=64, 3-bit XOR swizzle, LDS-staged epilogue ----------
// LDS[row][chunk c] = global[row][chunk c ^ (row&7)]; gll16 source pre-swizzled
// (lane l fetches chunk (l&7)^((l>>3)&7)); reads XOR the same -> conflict-free.
// Epilogue: C tile staged in LDS [128][136] bf16 (transposed for V/Vb), 16B stores.
__global__ __launch_bounds__(256) void gemm_qkv_kernel(
    const short* __restrict__ A, int lda, int K,
    const short* __restrict__ B0, const short* __restrict__ B1, const short* __restrict__ B2,
    const short* __restrict__ B3, const short* __restrict__ B4, const short* __restrict__ B5,
    const float* __restrict__ bias0, const float* __restrict__ bias1,
    const float* __restrict__ bias2, const float* __restrict__ bias3,
    const float* __restrict__ bias4, const float* __restrict__ bias5,
    short* __restrict__ outQ) {
  __shared__ short lds[128 * 136];  // 34.8 KB: K-loop uses [0,16384); epilogue all
  short* As = lds;                  // 128 x 64
  short* Bs = lds + 8192;           // 128 x 64
  const int tid = threadIdx.x;
  const int n0 = blockIdx.x * 128;
  const int m0 = blockIdx.y * 128;
  const short* Bp[6] = {B0, B1, B2, B3, B4, B5};
  const float* biasP[6] = {bias0, bias1, bias2, bias3, bias4, bias5};
  const int nsel = n0 >> 10;
  const int nc0 = n0 & 1023;
  const short* Bt = Bp[nsel] + (size_t)nc0 * K;
  const float* bsel = biasP[nsel];

  const int lane = tid & 63;
  const int w = tid >> 6;
  const int wm = (w >> 1) * 64;
  const int wn = (w & 1) * 64;
  const int lr = lane & 15;
  const int lg = lane >> 4;
  const int rl = lane >> 3;
  const int gch = (lane & 7) ^ (rl & 7);

  f32x4 acc[4][4];
  for (int a = 0; a < 4; ++a)
    for (int b = 0; b < 4; ++b) acc[a][b] = {0.f, 0.f, 0.f, 0.f};

  for (int k0 = 0; k0 < K; k0 += 64) {
    __syncthreads();
    for (int p = 0; p < 4; ++p) {
      int rb = (p * 4 + w) * 8;
      gll16(A + (size_t)(m0 + rb + rl) * lda + k0 + gch * 8, &As[rb * 64]);
      gll16(Bt + (size_t)(rb + rl) * K + k0 + gch * 8, &Bs[rb * 64]);
    }
    __syncthreads();
    for (int ks = 0; ks < 2; ++ks) {
      bfrag af[4], bf[4];
      for (int t = 0; t < 4; ++t) {
        af[t] = *reinterpret_cast<const bfrag*>(
            &As[(wm + t * 16 + lr) * 64 + (((lg + 4 * ks) ^ (lr & 7)) * 8)]);
        bf[t] = *reinterpret_cast<const bfrag*>(
            &Bs[(wn + t * 16 + lr) * 64 + (((lg + 4 * ks) ^ (lr & 7)) * 8)]);
      }
      for (int mt = 0; mt < 4; ++mt)
        for (int nt = 0; nt < 4; ++nt)
          acc[mt][nt] = __builtin_amdgcn_mfma_f32_16x16x32_bf16(af[mt], bf[nt], acc[mt][nt], 0, 0, 0);
    }
  }

  const float cmul = (nsel == 0 || nsel == 3) ? QSCALE : 1.0f;
  const bool tr = (nsel == 2 || nsel == 5);
  __syncthreads();
  for (int mt = 0; mt < 4; ++mt)
    for (int nt = 0; nt < 4; ++nt) {
      int c = wn + nt * 16 + lr;
      float bv = bsel[nc0 + c];
      for (int i = 0; i < 4; ++i) {
        int r = wm + mt * 16 + lg * 4 + i;
        short v16 = f2bf_n((acc[mt][nt][i] + bv) * cmul);
        if (tr) lds[c * 136 + r] = v16;
        else lds[r * 136 + c] = v16;
      }
    }
  __syncthreads();
  const int bb = m0 >> 11;
  const int sloc = m0 & 2047;
  const int hh0 = nc0 >> 6;
  short* basebuf = outQ + (size_t)nsel * ELTS_PER;
  for (int j = 0; j < 8; ++j) {
    int gid = j * 256 + tid;
    int rr = gid >> 4;
    int ch = gid & 15;
    s8v v = *reinterpret_cast<const s8v*>(&lds[rr * 136 + ch * 8]);
    if (tr) {
      int hh = hh0 + (rr >> 6), d = rr & 63;
      *reinterpret_cast<s8v*>(
          basebuf + ((size_t)(bb * NH + hh) * HD + d) * S_LEN + sloc + ch * 8) = v;
    } else {
      int hh = hh0 + (ch >> 3), d0 = (ch & 7) * 8;
      *reinterpret_cast<s8v*>(
          basebuf + ((size_t)(bb * NH + hh) * S_LEN + sloc + rr) * HD + d0) = v;
    }
  }
}

// ---------------- K-split GEMM (BK=64), f32 partial outputs ----------------
__global__ __launch_bounds__(256) void gemm_ksplit_kernel(
    const short* __restrict__ A0, const short* __restrict__ A1, int lda,
    const short* __restrict__ B, int ldb, int K,
    const float* __restrict__ bias, float* __restrict__ out0, float* __restrict__ out1) {
  __shared__ short lds[16384];
  short* As = lds;
  short* Bs = lds + 8192;
  const int tid = threadIdx.x;
  const int n0 = blockIdx.x * 128;
  const int m0 = blockIdx.y * 128;
  const int z = blockIdx.z;
  const short* A = z ? A1 : A0;
  const short* Bt = B + (size_t)n0 * ldb + z * K;
  float* outp = z ? out1 : out0;

  const int lane = tid & 63;
  const int w = tid >> 6;
  const int wm = (w >> 1) * 64;
  const int wn = (w & 1) * 64;
  const int lr = lane & 15;
  const int lg = lane >> 4;
  const int rl = lane >> 3;
  const int gch = (lane & 7) ^ (rl & 7);

  f32x4 acc[4][4];
  for (int a = 0; a < 4; ++a)
    for (int b = 0; b < 4; ++b) acc[a][b] = {0.f, 0.f, 0.f, 0.f};

  for (int k0 = 0; k0 < K; k0 += 64) {
    __syncthreads();
    for (int p = 0; p < 4; ++p) {
      int rb = (p * 4 + w) * 8;
      gll16(A + (size_t)(m0 + rb + rl) * lda + k0 + gch * 8, &As[rb * 64]);
      gll16(Bt + (size_t)(rb + rl) * ldb + k0 + gch * 8, &Bs[rb * 64]);
    }
    __syncthreads();
    for (int ks = 0; ks < 2; ++ks) {
      bfrag af[4], bf[4];
      for (int t = 0; t < 4; ++t) {
        af[t] = *reinterpret_cast<const bfrag*>(
            &As[(wm + t * 16 + lr) * 64 + (((lg + 4 * ks) ^ (lr & 7)) * 8)]);
        bf[t] = *reinterpret_cast<const bfrag*>(
            &Bs[(wn + t * 16 + lr) * 64 + (((lg + 4 * ks) ^ (lr & 7)) * 8)]);
      }
      for (int mt = 0; mt < 4; ++mt)
        for (int nt = 0; nt < 4; ++nt)
          acc[mt][nt] = __builtin_amdgcn_mfma_f32_16x16x32_bf16(af[mt], bf[nt], acc[mt][nt], 0, 0, 0);
    }
  }

  for (int mt = 0; mt < 4; ++mt)
    for (int nt = 0; nt < 4; ++nt)
      for (int i = 0; i < 4; ++i) {
        int row = m0 + wm + mt * 16 + lg * 4 + i;
        int col = n0 + wn + nt * 16 + lr;
        float v = acc[mt][nt][i] + (z == 0 ? bias[col] : 0.f);
        outp[(size_t)row * DMODEL + col] = v;
      }
}

// ---------------- causal flash attention fwd (v9: block-cooperative LDS staging) ------
// Block = 128 contiguous q-rows (4 waves x 32, EQUAL kt ranges 0..2j+1).
// Per k-tile: cooperative gll16 staging of K-tile and VT-tile into XOR-swizzled LDS.
// CU pairing: slots t and t+8 -> j and 15-j => constant per-CU work.
__global__ __launch_bounds__(256) void attn_fwd_kernel(const short* __restrict__ Q,
                                                       const short* __restrict__ Kk,
                                                       const short* __restrict__ VT,
                                                       short* __restrict__ fwd) {
  __shared__ short Kls[64 * 64];
  __shared__ short Vls[64 * 64];
  __shared__ short Ps[4][32 * 72];
  const int tid = threadIdx.x;
  const int lane = tid & 63;
  const int w = tid >> 6;
  const int lr = lane & 15;
  const int lg = lane >> 4;
  const int f = blockIdx.x;              // 0..511
  const int xcd = f & 7;
  const int s = f >> 3;                  // 0..63
  const int bhl = s & 3;
  const int t = s >> 2;                  // 0..15
  const int j = (t < 8) ? t : (23 - t);  // pair (t, t+8) -> j + (15-j)
  const int bh = xcd * 4 + bhl;
  const int b = bh >> 4;
  const int h = bh & 15;
  const size_t hb = (size_t)bh * S_LEN * HD;
  short* Pw = Ps[w];

  s8v onesi = {0x3F80, 0x3F80, 0x3F80, 0x3F80, 0x3F80, 0x3F80, 0x3F80, 0x3F80};
  bfrag onesv;
  __builtin_memcpy(&onesv, &onesi, 16);

  const int q0 = j * 128 + w * 32;
  const int ktmax = 2 * j + 1;

  const int rl8 = lane >> 3;
  const int gch = (lane & 7) ^ rl8;

  bfrag qf[2][2];
  for (int mt = 0; mt < 2; ++mt)
    for (int kc = 0; kc < 2; ++kc)
      qf[mt][kc] = *reinterpret_cast<const bfrag*>(
          Q + hb + (size_t)(q0 + mt * 16 + lr) * HD + kc * 32 + lg * 8);

  f32x4 oacc[2][4];
  for (int mt = 0; mt < 2; ++mt)
    for (int nd = 0; nd < 4; ++nd) oacc[mt][nd] = {0.f, 0.f, 0.f, 0.f};
  f32x4 osum[2];
  osum[0] = {0.f, 0.f, 0.f, 0.f};
  osum[1] = {0.f, 0.f, 0.f, 0.f};

  for (int kt = 0; kt <= ktmax; ++kt) {
    __syncthreads();
    const short* Kg = Kk + hb + (size_t)(kt * 64 + w * 16 + rl8) * HD + gch * 8;
    gll16(Kg, &Kls[(w * 16) * 64]);
    gll16(Kg + (size_t)8 * HD, &Kls[(w * 16 + 8) * 64]);
    const short* Vg = VT + hb + (size_t)(w * 16 + rl8) * S_LEN + kt * 64 + gch * 8;
    gll16(Vg, &Vls[(w * 16) * 64]);
    gll16(Vg + (size_t)8 * S_LEN, &Vls[(w * 16 + 8) * 64]);
    __syncthreads();
    bfrag kf[4][2];
    for (int nb = 0; nb < 4; ++nb)
      for (int kc = 0; kc < 2; ++kc)
        kf[nb][kc] = *reinterpret_cast<const bfrag*>(
            &Kls[(nb * 16 + lr) * 64 + (((kc * 4 + lg) ^ (lr & 7)) * 8)]);
    f32x4 sv[2][4];
    for (int mt = 0; mt < 2; ++mt)
      for (int nb = 0; nb < 4; ++nb) {
        f32x4 z = {0.f, 0.f, 0.f, 0.f};
        z = __builtin_amdgcn_mfma_f32_16x16x32_bf16(qf[mt][0], kf[nb][0], z, 0, 0, 0);
        sv[mt][nb] = __builtin_amdgcn_mfma_f32_16x16x32_bf16(qf[mt][1], kf[nb][1], z, 0, 0, 0);
      }
    if (kt * 64 + 63 > q0) {
      for (int mt = 0; mt < 2; ++mt)
        for (int nb = 0; nb < 4; ++nb)
          for (int i = 0; i < 4; ++i) {
            int colg = kt * 64 + nb * 16 + lr;
            int rowg = q0 + mt * 16 + lg * 4 + i;
            if (colg > rowg) sv[mt][nb][i] = -1e30f;
          }
    }
    for (int mt = 0; mt < 2; ++mt)
      for (int nb = 0; nb < 4; ++nb)
        for (int i = 0; i < 4; ++i)
          Pw[(mt * 16 + lg * 4 + i) * 72 + nb * 16 + lr] = f2bf_n(exp2f(sv[mt][nb][i]));
    bfrag vf[4][2];
    for (int nd = 0; nd < 4; ++nd)
      for (int kc = 0; kc < 2; ++kc)
        vf[nd][kc] = *reinterpret_cast<const bfrag*>(
            &Vls[(nd * 16 + lr) * 64 + (((kc * 4 + lg) ^ (lr & 7)) * 8)]);
    for (int mt = 0; mt < 2; ++mt) {
      bfrag pa0 = *reinterpret_cast<const bfrag*>(&Pw[(mt * 16 + lr) * 72 + lg * 8]);
      bfrag pa1 = *reinterpret_cast<const bfrag*>(&Pw[(mt * 16 + lr) * 72 + 32 + lg * 8]);
      for (int nd = 0; nd < 4; ++nd) {
        oacc[mt][nd] = __builtin_amdgcn_mfma_f32_16x16x32_bf16(pa0, vf[nd][0], oacc[mt][nd], 0, 0, 0);
        oacc[mt][nd] = __builtin_amdgcn_mfma_f32_16x16x32_bf16(pa1, vf[nd][1], oacc[mt][nd], 0, 0, 0);
      }
      osum[mt] = __builtin_amdgcn_mfma_f32_16x16x32_bf16(pa0, onesv, osum[mt], 0, 0, 0);
      osum[mt] = __builtin_amdgcn_mfma_f32_16x16x32_bf16(pa1, onesv, osum[mt], 0, 0, 0);
    }
  }

  for (int mt = 0; mt < 2; ++mt)
    for (int i = 0; i < 4; ++i) {
      int rowg = q0 + mt * 16 + lg * 4 + i;
      float inv = 1.0f / osum[mt][i];
      for (int nd = 0; nd < 4; ++nd)
        fwd[(size_t)(b * S_LEN + rowg) * DMODEL + h * HD + nd * 16 + lr] =
            f2bf(oacc[mt][nd][i] * inv);
    }
}

// ---------------- windowed backward attention (MFMA single-tile) ----------------
__global__ __launch_bounds__(256) void attn_bwd_kernel(const short* __restrict__ Qb,
                                                       const short* __restrict__ Kb,
                                                       const short* __restrict__ VT,
                                                       short* __restrict__ bwd) {
  __shared__ short Ps[4][32 * 72];
  const int tid = threadIdx.x;
  const int lane = tid & 63;
  const int w = tid >> 6;
  const int lr = lane & 15;
  const int lg = lane >> 4;
  const int h = blockIdx.y;
  const int b = blockIdx.z;
  const size_t hb = (size_t)(b * NH + h) * S_LEN * HD;
  const int q0 = blockIdx.x * 128 + w * 32;
  short* Pw = Ps[w];

  bfrag qf[2][2];
  for (int mt = 0; mt < 2; ++mt)
    for (int kc = 0; kc < 2; ++kc)
      qf[mt][kc] = *reinterpret_cast<const bfrag*>(
          Qb + hb + (size_t)(q0 + mt * 16 + lr) * HD + kc * 32 + lg * 8);
  bfrag kf[4][2];
  for (int nb = 0; nb < 4; ++nb) {
    int kr = q0 + nb * 16 + lr;
    kr = min(kr, S_LEN - 1);
    for (int kc = 0; kc < 2; ++kc)
      kf[nb][kc] = *reinterpret_cast<const bfrag*>(
          Kb + hb + (size_t)kr * HD + kc * 32 + lg * 8);
  }
  f32x4 sv[2][4];
  for (int mt = 0; mt < 2; ++mt)
    for (int nb = 0; nb < 4; ++nb) {
      f32x4 z = {0.f, 0.f, 0.f, 0.f};
      z = __builtin_amdgcn_mfma_f32_16x16x32_bf16(qf[mt][0], kf[nb][0], z, 0, 0, 0);
      sv[mt][nb] = __builtin_amdgcn_mfma_f32_16x16x32_bf16(qf[mt][1], kf[nb][1], z, 0, 0, 0);
    }
  float mx[2][4];
  for (int mt = 0; mt < 2; ++mt)
    for (int i = 0; i < 4; ++i) {
      int rowg = q0 + mt * 16 + lg * 4 + i;
      float m = -1e30f;
      for (int nb = 0; nb < 4; ++nb) {
        int colg = q0 + nb * 16 + lr;
        float t = sv[mt][nb][i];
        bool valid = (colg > rowg) && (colg <= rowg + 32) && (colg < S_LEN);
        if (!valid) t = -1e30f;
        sv[mt][nb][i] = t;
        m = fmaxf(m, t);
      }
      mx[mt][i] = m;
    }
  for (int off = 1; off < 16; off <<= 1)
    for (int mt = 0; mt < 2; ++mt)
      for (int i = 0; i < 4; ++i) mx[mt][i] = fmaxf(mx[mt][i], __shfl_xor(mx[mt][i], off));
  float rs[2][4] = {{0.f, 0.f, 0.f, 0.f}, {0.f, 0.f, 0.f, 0.f}};
  for (int mt = 0; mt < 2; ++mt)
    for (int nb = 0; nb < 4; ++nb)
      for (int i = 0; i < 4; ++i) {
        float p = exp2f(sv[mt][nb][i] - mx[mt][i]);
        rs[mt][i] += p;
        Pw[(mt * 16 + lg * 4 + i) * 72 + nb * 16 + lr] = f2bf_n(p);
      }
  for (int off = 1; off < 16; off <<= 1)
    for (int mt = 0; mt < 2; ++mt)
      for (int i = 0; i < 4; ++i) rs[mt][i] += __shfl_xor(rs[mt][i], off);
  bfrag vf[4][2];
  for (int nd = 0; nd < 4; ++nd)
    for (int kc = 0; kc < 2; ++kc) {
      int sbase = q0 + kc * 32 + lg * 8;
      sbase = min(sbase, S_LEN - 8);
      vf[nd][kc] = *reinterpret_cast<const bfrag*>(
          VT + hb + (size_t)(nd * 16 + lr) * S_LEN + sbase);
    }
  f32x4 oacc[2][4];
  for (int mt = 0; mt < 2; ++mt)
    for (int nd = 0; nd < 4; ++nd) oacc[mt][nd] = {0.f, 0.f, 0.f, 0.f};
  for (int mt = 0; mt < 2; ++mt) {
    bfrag pa0 = *reinterpret_cast<const bfrag*>(&Pw[(mt * 16 + lr) * 72 + lg * 8]);
    bfrag pa1 = *reinterpret_cast<const bfrag*>(&Pw[(mt * 16 + lr) * 72 + 32 + lg * 8]);
    for (int nd = 0; nd < 4; ++nd) {
      oacc[mt][nd] = __builtin_amdgcn_mfma_f32_16x16x32_bf16(pa0, vf[nd][0], oacc[mt][nd], 0, 0, 0);
      oacc[mt][nd] = __builtin_amdgcn_mfma_f32_16x16x32_bf16(pa1, vf[nd][1], oacc[mt][nd], 0, 0, 0);
    }
  }
  for (int mt = 0; mt < 2; ++mt)
    for (int nd = 0; nd < 4; ++nd)
      for (int i = 0; i < 4; ++i) {
        int rowg = q0 + mt * 16 + lg * 4 + i;
        float ov = oacc[mt][nd][i] / rs[mt][i];
        bwd[(size_t)(b * S_LEN + rowg) * DMODEL + h * HD + nd * 16 + lr] = f2bf(ov);
      }
}

// ---------------- row S-1 of bwd: uniform mean over all Vb keys ----------------
__global__ __launch_bounds__(256) void vmean_kernel(const short* __restrict__ VT,
                                                    short* __restrict__ bwd) {
  __shared__ float red[256];
  const int bh = blockIdx.x;  // b*NH + h
  const int d = threadIdx.x >> 2;
  const int seg = threadIdx.x & 3;
  const short* row = VT + (size_t)bh * S_LEN * HD + (size_t)d * S_LEN + seg * 512;
  float s = 0.f;
  for (int j = 0; j < 512; j += 8) {
    uint4 v = *reinterpret_cast<const uint4*>(row + j);
    s += bflo(v.x) + bfhi(v.x) + bflo(v.y) + bfhi(v.y) +
         bflo(v.z) + bfhi(v.z) + bflo(v.w) + bfhi(v.w);
  }
  red[threadIdx.x] = s;
  __syncthreads();
  if (seg == 0) {
    float t = red[d * 4] + red[d * 4 + 1] + red[d * 4 + 2] + red[d * 4 + 3];
    int b = bh >> 4, h = bh & 15;
    bwd[((size_t)(b * S_LEN + S_LEN - 1)) * DMODEL + h * HD + d] = f2bf(t * (1.f / S_LEN));
  }
}

// ---------------- gate LN + sigmoid + fuse (sums 2 partials) ----------------
__global__ __launch_bounds__(256) void ln_gate_fuse_kernel(
    const float* __restrict__ g0p, const float* __restrict__ g1p,
    const float* __restrict__ gln_g, const float* __restrict__ gln_b,
    const short* __restrict__ fwd, const short* __restrict__ bwd,
    const float* __restrict__ bstr, short* __restrict__ fused) {
  __shared__ float red[8];
  const int row = blockIdx.x;
  const int tid = threadIdx.x;
  const int lane = tid & 63;
  const int w = tid >> 6;
  float4 x0 = *reinterpret_cast<const float4*>(g0p + (size_t)row * DMODEL + tid * 4);
  float4 x1 = *reinterpret_cast<const float4*>(g1p + (size_t)row * DMODEL + tid * 4);
  float xa[4] = {x0.x + x1.x, x0.y + x1.y, x0.z + x1.z, x0.w + x1.w};
  float s = xa[0] + xa[1] + xa[2] + xa[3];
  float ss = xa[0] * xa[0] + xa[1] * xa[1] + xa[2] * xa[2] + xa[3] * xa[3];
  for (int off = 1; off < 64; off <<= 1) {
    s += __shfl_xor(s, off);
    ss += __shfl_xor(ss, off);
  }
  if (lane == 0) { red[w] = s; red[4 + w] = ss; }
  __syncthreads();
  s = red[0] + red[1] + red[2] + red[3];
  ss = red[4] + red[5] + red[6] + red[7];
  const float mean = s * (1.f / DMODEL);
  const float var = ss * (1.f / DMODEL) - mean * mean;
  const float rstd = rsqrtf(var + 1e-5f);
  const float strength = 0.3f / (1.f + __expf(-bstr[0]));
  for (int e = 0; e < 4; ++e) {
    int idx = tid * 4 + e;
    float g = (xa[e] - mean) * rstd * gln_g[idx] + gln_b[idx];
    float gate = 1.f / (1.f + __expf(-g));
    float f = bf2f(fwd[(size_t)row * DMODEL + idx]) +
              strength * gate * bf2f(bwd[(size_t)row * DMODEL + idx]);
    fused[(size_t)row * DMODEL + idx] = f2bf(f);
  }
}

// ---------------- final residual LN (sums 2 partials) ----------------
__global__ __launch_bounds__(256) void final_ln_kernel(const float* __restrict__ x,
                                                       const float* __restrict__ o0p,
                                                       const float* __restrict__ o1p,
                                                       const float* __restrict__ ln_g,
                                                       const float* __restrict__ ln_b,
                                                       float* __restrict__ y) {
  __shared__ float red[8];
  const int row = blockIdx.x;
  const int tid = threadIdx.x;
  const int lane = tid & 63;
  const int w = tid >> 6;
  float4 xv = *reinterpret_cast<const float4*>(x + (size_t)row * DMODEL + tid * 4);
  float4 o0 = *reinterpret_cast<const float4*>(o0p + (size_t)row * DMODEL + tid * 4);
  float4 o1 = *reinterpret_cast<const float4*>(o1p + (size_t)row * DMODEL + tid * 4);
  float t[4] = {xv.x + o0.x + o1.x, xv.y + o0.y + o1.y,
                xv.z + o0.z + o1.z, xv.w + o0.w + o1.w};
  float s = t[0] + t[1] + t[2] + t[3];
  float ss = t[0] * t[0] + t[1] * t[1] + t[2] * t[2] + t[3] * t[3];
  for (int off = 1; off < 64; off <<= 1) {
    s += __shfl_xor(s, off);
    ss += __shfl_xor(ss, off);
  }
  if (lane == 0) { red[w] = s; red[4 + w] = ss; }
  __syncthreads();
  s = red[0] + red[1] + red[2] + red[3];
  ss = red[4] + red[5] + red[6] + red[7];
  const float mean = s * (1.f / DMODEL);
  const float var = ss * (1.f / DMODEL) - mean * mean;
  const float rstd = rsqrtf(var + 1e-5f);
  for (int e = 0; e < 4; ++e) {
    int idx = tid * 4 + e;
    y[(size_t)row * DMODEL + idx] = (t[e] - mean) * rstd * ln_g[idx] + ln_b[idx];
  }
}

extern "C" void kernel_launch(void* const* d_in, const int* in_sizes, int n_in,
                              void* d_out, int out_size, void* d_ws, size_t ws_size,
                              hipStream_t stream) {
  const float* x = (const float*)d_in[0];
  const float* fq_w = (const float*)d_in[1];
  const float* fq_b = (const float*)d_in[2];
  const float* fk_w = (const float*)d_in[3];
  const float* fk_b = (const float*)d_in[4];
  const float* fv_w = (const float*)d_in[5];
  const float* fv_b = (const float*)d_in[6];
  const float* bq_w = (const float*)d_in[7];
  const float* bq_b = (const float*)d_in[8];
  const float* bk_w = (const float*)d_in[9];
  const float* bk_b = (const float*)d_in[10];
  const float* bv_w = (const float*)d_in[11];
  const float* bv_b = (const float*)d_in[12];
  const float* gate_w = (const float*)d_in[13];
  const float* gate_b = (const float*)d_in[14];
  const float* gln_g = (const float*)d_in[15];
  const float* gln_b = (const float*)d_in[16];
  const float* bstr = (const float*)d_in[17];
  const float* out_w = (const float*)d_in[18];
  const float* out_b = (const float*)d_in[19];
  const float* ln_g = (const float*)d_in[20];
  const float* ln_b = (const float*)d_in[21];

  char* ws = (char*)d_ws;
  const size_t MB = 1u << 20;
  short* xb = (short*)(ws + 0);
  short* wT0 = (short*)(ws + 8 * MB);
  short* wT1 = (short*)(ws + 10 * MB);
  short* wT2 = (short*)(ws + 12 * MB);
  short* wT3 = (short*)(ws + 14 * MB);
  short* wT4 = (short*)(ws + 16 * MB);
  short* wT5 = (short*)(ws + 18 * MB);
  short* gwT = (short*)(ws + 20 * MB);
  short* owT = (short*)(ws + 24 * MB);
  short* qkv = (short*)(ws + 26 * MB);
  short* fwd = (short*)(ws + 0);
  short* bwdb = (short*)(ws + 8 * MB);
  float* G0 = (float*)(ws + 26 * MB);
  float* G1 = (float*)(ws + 42 * MB);
  short* fused = (short*)(ws + 58 * MB);
  float* O0 = (float*)(ws + 26 * MB);
  float* O1 = (float*)(ws + 42 * MB);

  prep_kernel<<<dim3(32, 64, 9), dim3(32, 8), 0, stream>>>(
      fq_w, fk_w, fv_w, bq_w, bk_w, bv_w, out_w, gate_w,
      wT0, wT1, wT2, wT3, wT4, wT5, owT, gwT, x, xb);

  gemm_qkv_kernel<<<dim3(48, 32), 256, 0, stream>>>(
      xb, 1024, 1024, wT0, wT1, wT2, wT3, wT4, wT5,
      fq_b, fk_b, fv_b, bq_b, bk_b, bv_b, qkv);

  attn_fwd_kernel<<<512, 256, 0, stream>>>(
      qkv, qkv + (size_t)ELTS_PER, qkv + 2 * (size_t)ELTS_PER, fwd);
  attn_bwd_kernel<<<dim3(16, 16, 2), 256, 0, stream>>>(
      qkv + 3 * (size_t)ELTS_PER, qkv + 4 * (size_t)ELTS_PER, qkv + 5 * (size_t)ELTS_PER, bwdb);
  vmean_kernel<<<32, 256, 0, stream>>>(qkv + 5 * (size_t)ELTS_PER, bwdb);

  gemm_ksplit_kernel<<<dim3(8, 32, 2), 256, 0, stream>>>(
      fwd, bwdb, 1024, gwT, 2048, 1024, gate_b, G0, G1);

  ln_gate_fuse_kernel<<<4096, 256, 0, stream>>>(G0, G1, gln_g, gln_b, fwd, bwdb, bstr, fused);

  gemm_ksplit_kernel<<<dim3(8, 32, 2), 256, 0, stream>>>(
      fused, fused + 512, 1024, owT, 1024, 512, out_b, O0, O1);

  final_ln_kernel<<<4096, 256, 0, stream>>>(x, O0, O1, ln_g, ln_b, (float*)d_out);
}

// Round 17
// 228.226 us; speedup vs baseline: 1.1461x; 1.0838x over previous
//
#include <hip/hip_runtime.h>

#define S_LEN 2048
#define NH 16
#define HD 64
#define DMODEL 1024
#define NTOK 4096
#define ELTS_PER 4194304  // B*S*D = NTOK*DMODEL
#define QSCALE 0.18033688f  // 0.125 * log2(e), folded into Q/Qb projections

typedef __attribute__((ext_vector_type(8))) __bf16 bfrag;
typedef __attribute__((ext_vector_type(8))) short s8v;
typedef __attribute__((ext_vector_type(4))) float f32x4;

__device__ inline float bf2f(short s) {
  unsigned int u = ((unsigned int)(unsigned short)s) << 16;
  float f;
  __builtin_memcpy(&f, &u, 4);
  return f;
}
__device__ inline short f2bf(float f) {
  unsigned int u;
  __builtin_memcpy(&u, &f, 4);
  u = (u + 0x7fffu + ((u >> 16) & 1u)) >> 16;
  return (short)u;
}
__device__ inline short f2bf_n(float f) {  // native convert (packed cvt)
  __bf16 h = (__bf16)f;
  short s;
  __builtin_memcpy(&s, &h, 2);
  return s;
}
__device__ inline float bflo(unsigned int u) {
  unsigned int t = u << 16;
  float f; __builtin_memcpy(&f, &t, 4); return f;
}
__device__ inline float bfhi(unsigned int u) {
  unsigned int t = u & 0xffff0000u;
  float f; __builtin_memcpy(&f, &t, 4); return f;
}
// async global -> LDS, 16B per lane (dest = wave-uniform base + lane*16)
__device__ __forceinline__ void gll16(const short* g, short* l) {
  __builtin_amdgcn_global_load_lds(
      (const __attribute__((address_space(1))) void*)g,
      (__attribute__((address_space(3))) void*)l, 16, 0, 0);
}

// ---- prep: z<8 -> transpose+convert weights f32 [K][1024] -> bf16 [1024][K];
//      z==8 -> convert x f32 -> bf16 (8 elems/thread) ----
__global__ void prep_kernel(const float* __restrict__ s0, const float* __restrict__ s1,
                            const float* __restrict__ s2, const float* __restrict__ s3,
                            const float* __restrict__ s4, const float* __restrict__ s5,
                            const float* __restrict__ s6, const float* __restrict__ s7,
                            short* d0, short* d1, short* d2, short* d3,
                            short* d4, short* d5, short* d6, short* d7,
                            const float* __restrict__ xin, short* __restrict__ xout) {
  const int z = blockIdx.z;
  if (z == 8) {
    int bid = blockIdx.y * 32 + blockIdx.x;                 // 0..2047
    int t256 = threadIdx.y * 32 + threadIdx.x;
    int i = (bid * 256 + t256) * 8;
    float4 v0 = *reinterpret_cast<const float4*>(xin + i);
    float4 v1 = *reinterpret_cast<const float4*>(xin + i + 4);
    short o[8] = {f2bf(v0.x), f2bf(v0.y), f2bf(v0.z), f2bf(v0.w),
                  f2bf(v1.x), f2bf(v1.y), f2bf(v1.z), f2bf(v1.w)};
    s8v ov;
    __builtin_memcpy(&ov, o, 16);
    *reinterpret_cast<s8v*>(xout + i) = ov;
    return;
  }
  const int K = (z == 7) ? 2048 : 1024;
  if (blockIdx.y * 32 >= K) return;
  const float* srcs[8] = {s0, s1, s2, s3, s4, s5, s6, s7};
  short* dsts[8] = {d0, d1, d2, d3, d4, d5, d6, d7};
  const float* in = srcs[z];
  short* out = dsts[z];
  __shared__ float tile[32][33];
  int nb = blockIdx.x * 32, kb = blockIdx.y * 32;
  int tx = threadIdx.x, ty = threadIdx.y;  // block (32,8)
  for (int j = 0; j < 32; j += 8)
    tile[ty + j][tx] = in[(size_t)(kb + ty + j) * 1024 + nb + tx];
  __syncthreads();
  for (int j = 0; j < 32; j += 8)
    out[(size_t)(nb + ty + j) * K + kb + tx] = f2bf(tile[tx][ty + j]);
}

// ---------------- QKV GEMM: BK=64, 3-bit XOR swizzle, LDS-staged epilogue ----------
__global__ __launch_bounds__(256) void gemm_qkv_kernel(
    const short* __restrict__ A, int lda, int K,
    const short* __restrict__ B0, const short* __restrict__ B1, const short* __restrict__ B2,
    const short* __restrict__ B3, const short* __restrict__ B4, const short* __restrict__ B5,
    const float* __restrict__ bias0, const float* __restrict__ bias1,
    const float* __restrict__ bias2, const float* __restrict__ bias3,
    const float* __restrict__ bias4, const float* __restrict__ bias5,
    short* __restrict__ outQ) {
  __shared__ short lds[128 * 136];  // 34.8 KB: K-loop uses [0,16384); epilogue all
  short* As = lds;                  // 128 x 64
  short* Bs = lds + 8192;           // 128 x 64
  const int tid = threadIdx.x;
  const int n0 = blockIdx.x * 128;
  const int m0 = blockIdx.y * 128;
  const short* Bp[6] = {B0, B1, B2, B3, B4, B5};
  const float* biasP[6] = {bias0, bias1, bias2, bias3, bias4, bias5};
  const int nsel = n0 >> 10;
  const int nc0 = n0 & 1023;
  const short* Bt = Bp[nsel] + (size_t)nc0 * K;
  const float* bsel = biasP[nsel];

  const int lane = tid & 63;
  const int w = tid >> 6;
  const int wm = (w >> 1) * 64;
  const int wn = (w & 1) * 64;
  const int lr = lane & 15;
  const int lg = lane >> 4;
  const int rl = lane >> 3;
  const int gch = (lane & 7) ^ (rl & 7);

  f32x4 acc[4][4];
  for (int a = 0; a < 4; ++a)
    for (int b = 0; b < 4; ++b) acc[a][b] = {0.f, 0.f, 0.f, 0.f};

  for (int k0 = 0; k0 < K; k0 += 64) {
    __syncthreads();
    for (int p = 0; p < 4; ++p) {
      int rb = (p * 4 + w) * 8;
      gll16(A + (size_t)(m0 + rb + rl) * lda + k0 + gch * 8, &As[rb * 64]);
      gll16(Bt + (size_t)(rb + rl) * K + k0 + gch * 8, &Bs[rb * 64]);
    }
    __syncthreads();
    for (int ks = 0; ks < 2; ++ks) {
      bfrag af[4], bf[4];
      for (int t = 0; t < 4; ++t) {
        af[t] = *reinterpret_cast<const bfrag*>(
            &As[(wm + t * 16 + lr) * 64 + (((lg + 4 * ks) ^ (lr & 7)) * 8)]);
        bf[t] = *reinterpret_cast<const bfrag*>(
            &Bs[(wn + t * 16 + lr) * 64 + (((lg + 4 * ks) ^ (lr & 7)) * 8)]);
      }
      for (int mt = 0; mt < 4; ++mt)
        for (int nt = 0; nt < 4; ++nt)
          acc[mt][nt] = __builtin_amdgcn_mfma_f32_16x16x32_bf16(af[mt], bf[nt], acc[mt][nt], 0, 0, 0);
    }
  }

  const float cmul = (nsel == 0 || nsel == 3) ? QSCALE : 1.0f;
  const bool tr = (nsel == 2 || nsel == 5);
  __syncthreads();
  for (int mt = 0; mt < 4; ++mt)
    for (int nt = 0; nt < 4; ++nt) {
      int c = wn + nt * 16 + lr;
      float bv = bsel[nc0 + c];
      for (int i = 0; i < 4; ++i) {
        int r = wm + mt * 16 + lg * 4 + i;
        short v16 = f2bf_n((acc[mt][nt][i] + bv) * cmul);
        if (tr) lds[c * 136 + r] = v16;
        else lds[r * 136 + c] = v16;
      }
    }
  __syncthreads();
  const int bb = m0 >> 11;
  const int sloc = m0 & 2047;
  const int hh0 = nc0 >> 6;
  short* basebuf = outQ + (size_t)nsel * ELTS_PER;
  for (int j = 0; j < 8; ++j) {
    int gid = j * 256 + tid;
    int rr = gid >> 4;
    int ch = gid & 15;
    s8v v = *reinterpret_cast<const s8v*>(&lds[rr * 136 + ch * 8]);
    if (tr) {
      int hh = hh0 + (rr >> 6), d = rr & 63;
      *reinterpret_cast<s8v*>(
          basebuf + ((size_t)(bb * NH + hh) * HD + d) * S_LEN + sloc + ch * 8) = v;
    } else {
      int hh = hh0 + (ch >> 3), d0 = (ch & 7) * 8;
      *reinterpret_cast<s8v*>(
          basebuf + ((size_t)(bb * NH + hh) * S_LEN + sloc + rr) * HD + d0) = v;
    }
  }
}

// ---------------- K-split GEMM (BK=64), f32 partial outputs ----------------
__global__ __launch_bounds__(256) void gemm_ksplit_kernel(
    const short* __restrict__ A0, const short* __restrict__ A1, int lda,
    const short* __restrict__ B, int ldb, int K,
    const float* __restrict__ bias, float* __restrict__ out0, float* __restrict__ out1) {
  __shared__ short lds[16384];
  short* As = lds;
  short* Bs = lds + 8192;
  const int tid = threadIdx.x;
  const int n0 = blockIdx.x * 128;
  const int m0 = blockIdx.y * 128;
  const int z = blockIdx.z;
  const short* A = z ? A1 : A0;
  const short* Bt = B + (size_t)n0 * ldb + z * K;
  float* outp = z ? out1 : out0;

  const int lane = tid & 63;
  const int w = tid >> 6;
  const int wm = (w >> 1) * 64;
  const int wn = (w & 1) * 64;
  const int lr = lane & 15;
  const int lg = lane >> 4;
  const int rl = lane >> 3;
  const int gch = (lane & 7) ^ (rl & 7);

  f32x4 acc[4][4];
  for (int a = 0; a < 4; ++a)
    for (int b = 0; b < 4; ++b) acc[a][b] = {0.f, 0.f, 0.f, 0.f};

  for (int k0 = 0; k0 < K; k0 += 64) {
    __syncthreads();
    for (int p = 0; p < 4; ++p) {
      int rb = (p * 4 + w) * 8;
      gll16(A + (size_t)(m0 + rb + rl) * lda + k0 + gch * 8, &As[rb * 64]);
      gll16(Bt + (size_t)(rb + rl) * ldb + k0 + gch * 8, &Bs[rb * 64]);
    }
    __syncthreads();
    for (int ks = 0; ks < 2; ++ks) {
      bfrag af[4], bf[4];
      for (int t = 0; t < 4; ++t) {
        af[t] = *reinterpret_cast<const bfrag*>(
            &As[(wm + t * 16 + lr) * 64 + (((lg + 4 * ks) ^ (lr & 7)) * 8)]);
        bf[t] = *reinterpret_cast<const bfrag*>(
            &Bs[(wn + t * 16 + lr) * 64 + (((lg + 4 * ks) ^ (lr & 7)) * 8)]);
      }
      for (int mt = 0; mt < 4; ++mt)
        for (int nt = 0; nt < 4; ++nt)
          acc[mt][nt] = __builtin_amdgcn_mfma_f32_16x16x32_bf16(af[mt], bf[nt], acc[mt][nt], 0, 0, 0);
    }
  }

  for (int mt = 0; mt < 4; ++mt)
    for (int nt = 0; nt < 4; ++nt)
      for (int i = 0; i < 4; ++i) {
        int row = m0 + wm + mt * 16 + lg * 4 + i;
        int col = n0 + wn + nt * 16 + lr;
        float v = acc[mt][nt][i] + (z == 0 ? bias[col] : 0.f);
        outp[(size_t)row * DMODEL + col] = v;
      }
}

// ---------------- fused attention: fwd (0..511) + bwd (512..1023) + vmean (1024..1055) --
// fwd: block-cooperative LDS staging, 4 waves x 32 rows, XOR-swizzled K/VT tiles.
// bwd: windowed single-tile MFMA. vmean: uniform mean over all Vb keys for row S-1.
// Block-uniform branch on blockIdx.x -> barriers legal per branch.
__global__ __launch_bounds__(256) void attn_all_kernel(const short* __restrict__ Q,
                                                       const short* __restrict__ Kk,
                                                       const short* __restrict__ VT,
                                                       const short* __restrict__ Qb,
                                                       const short* __restrict__ Kb,
                                                       const short* __restrict__ VbT,
                                                       short* __restrict__ fwd,
                                                       short* __restrict__ bwd) {
  __shared__ short Kls[64 * 64];
  __shared__ short Vls[64 * 64];
  __shared__ short Ps[4][32 * 72];
  __shared__ float red[256];
  const int tid = threadIdx.x;
  const int lane = tid & 63;
  const int w = tid >> 6;
  const int lr = lane & 15;
  const int lg = lane >> 4;

  if (blockIdx.x >= 1024) {
    // ---------------- vmean ----------------
    const int bh = blockIdx.x - 1024;  // b*NH + h
    const int d = tid >> 2;
    const int seg = tid & 3;
    const short* row = VbT + (size_t)bh * S_LEN * HD + (size_t)d * S_LEN + seg * 512;
    float s = 0.f;
    for (int j = 0; j < 512; j += 8) {
      uint4 v = *reinterpret_cast<const uint4*>(row + j);
      s += bflo(v.x) + bfhi(v.x) + bflo(v.y) + bfhi(v.y) +
           bflo(v.z) + bfhi(v.z) + bflo(v.w) + bfhi(v.w);
    }
    red[tid] = s;
    __syncthreads();
    if (seg == 0) {
      float t = red[d * 4] + red[d * 4 + 1] + red[d * 4 + 2] + red[d * 4 + 3];
      int b = bh >> 4, h = bh & 15;
      bwd[((size_t)(b * S_LEN + S_LEN - 1)) * DMODEL + h * HD + d] = f2bf(t * (1.f / S_LEN));
    }
    return;
  }

  if (blockIdx.x >= 512) {
    // ---------------- windowed backward attention ----------------
    const int idx = blockIdx.x - 512;
    const int bx = idx & 15;
    const int h = (idx >> 4) & 15;
    const int b = idx >> 8;
    const size_t hb = (size_t)(b * NH + h) * S_LEN * HD;
    const int q0 = bx * 128 + w * 32;
    short* Pw = Ps[w];

    bfrag qf[2][2];
    for (int mt = 0; mt < 2; ++mt)
      for (int kc = 0; kc < 2; ++kc)
        qf[mt][kc] = *reinterpret_cast<const bfrag*>(
            Qb + hb + (size_t)(q0 + mt * 16 + lr) * HD + kc * 32 + lg * 8);
    bfrag kf[4][2];
    for (int nb = 0; nb < 4; ++nb) {
      int kr = q0 + nb * 16 + lr;
      kr = min(kr, S_LEN - 1);
      for (int kc = 0; kc < 2; ++kc)
        kf[nb][kc] = *reinterpret_cast<const bfrag*>(
            Kb + hb + (size_t)kr * HD + kc * 32 + lg * 8);
    }
    f32x4 sv[2][4];
    for (int mt = 0; mt < 2; ++mt)
      for (int nb = 0; nb < 4; ++nb) {
        f32x4 z = {0.f, 0.f, 0.f, 0.f};
        z = __builtin_amdgcn_mfma_f32_16x16x32_bf16(qf[mt][0], kf[nb][0], z, 0, 0, 0);
        sv[mt][nb] = __builtin_amdgcn_mfma_f32_16x16x32_bf16(qf[mt][1], kf[nb][1], z, 0, 0, 0);
      }
    float mx[2][4];
    for (int mt = 0; mt < 2; ++mt)
      for (int i = 0; i < 4; ++i) {
        int rowg = q0 + mt * 16 + lg * 4 + i;
        float m = -1e30f;
        for (int nb = 0; nb < 4; ++nb) {
          int colg = q0 + nb * 16 + lr;
          float t = sv[mt][nb][i];
          bool valid = (colg > rowg) && (colg <= rowg + 32) && (colg < S_LEN);
          if (!valid) t = -1e30f;
          sv[mt][nb][i] = t;
          m = fmaxf(m, t);
        }
        mx[mt][i] = m;
      }
    for (int off = 1; off < 16; off <<= 1)
      for (int mt = 0; mt < 2; ++mt)
        for (int i = 0; i < 4; ++i) mx[mt][i] = fmaxf(mx[mt][i], __shfl_xor(mx[mt][i], off));
    float rs[2][4] = {{0.f, 0.f, 0.f, 0.f}, {0.f, 0.f, 0.f, 0.f}};
    for (int mt = 0; mt < 2; ++mt)
      for (int nb = 0; nb < 4; ++nb)
        for (int i = 0; i < 4; ++i) {
          float p = exp2f(sv[mt][nb][i] - mx[mt][i]);
          rs[mt][i] += p;
          Pw[(mt * 16 + lg * 4 + i) * 72 + nb * 16 + lr] = f2bf_n(p);
        }
    for (int off = 1; off < 16; off <<= 1)
      for (int mt = 0; mt < 2; ++mt)
        for (int i = 0; i < 4; ++i) rs[mt][i] += __shfl_xor(rs[mt][i], off);
    bfrag vf[4][2];
    for (int nd = 0; nd < 4; ++nd)
      for (int kc = 0; kc < 2; ++kc) {
        int sbase = q0 + kc * 32 + lg * 8;
        sbase = min(sbase, S_LEN - 8);
        vf[nd][kc] = *reinterpret_cast<const bfrag*>(
            VbT + hb + (size_t)(nd * 16 + lr) * S_LEN + sbase);
      }
    f32x4 oacc[2][4];
    for (int mt = 0; mt < 2; ++mt)
      for (int nd = 0; nd < 4; ++nd) oacc[mt][nd] = {0.f, 0.f, 0.f, 0.f};
    for (int mt = 0; mt < 2; ++mt) {
      bfrag pa0 = *reinterpret_cast<const bfrag*>(&Pw[(mt * 16 + lr) * 72 + lg * 8]);
      bfrag pa1 = *reinterpret_cast<const bfrag*>(&Pw[(mt * 16 + lr) * 72 + 32 + lg * 8]);
      for (int nd = 0; nd < 4; ++nd) {
        oacc[mt][nd] = __builtin_amdgcn_mfma_f32_16x16x32_bf16(pa0, vf[nd][0], oacc[mt][nd], 0, 0, 0);
        oacc[mt][nd] = __builtin_amdgcn_mfma_f32_16x16x32_bf16(pa1, vf[nd][1], oacc[mt][nd], 0, 0, 0);
      }
    }
    for (int mt = 0; mt < 2; ++mt)
      for (int nd = 0; nd < 4; ++nd)
        for (int i = 0; i < 4; ++i) {
          int rowg = q0 + mt * 16 + lg * 4 + i;
          float ov = oacc[mt][nd][i] / rs[mt][i];
          bwd[(size_t)(b * S_LEN + rowg) * DMODEL + h * HD + nd * 16 + lr] = f2bf(ov);
        }
    return;
  }

  // ---------------- causal flash attention fwd ----------------
  const int f = blockIdx.x;              // 0..511
  const int xcd = f & 7;
  const int s = f >> 3;                  // 0..63
  const int bhl = s & 3;
  const int t = s >> 2;                  // 0..15
  const int j = (t < 8) ? t : (23 - t);  // pair (t, t+8) -> j + (15-j)
  const int bh = xcd * 4 + bhl;
  const int b = bh >> 4;
  const int h = bh & 15;
  const size_t hb = (size_t)bh * S_LEN * HD;
  short* Pw = Ps[w];

  s8v onesi = {0x3F80, 0x3F80, 0x3F80, 0x3F80, 0x3F80, 0x3F80, 0x3F80, 0x3F80};
  bfrag onesv;
  __builtin_memcpy(&onesv, &onesi, 16);

  const int q0 = j * 128 + w * 32;
  const int ktmax = 2 * j + 1;

  const int rl8 = lane >> 3;
  const int gch = (lane & 7) ^ rl8;

  bfrag qf[2][2];
  for (int mt = 0; mt < 2; ++mt)
    for (int kc = 0; kc < 2; ++kc)
      qf[mt][kc] = *reinterpret_cast<const bfrag*>(
          Q + hb + (size_t)(q0 + mt * 16 + lr) * HD + kc * 32 + lg * 8);

  f32x4 oacc[2][4];
  for (int mt = 0; mt < 2; ++mt)
    for (int nd = 0; nd < 4; ++nd) oacc[mt][nd] = {0.f, 0.f, 0.f, 0.f};
  f32x4 osum[2];
  osum[0] = {0.f, 0.f, 0.f, 0.f};
  osum[1] = {0.f, 0.f, 0.f, 0.f};

  for (int kt = 0; kt <= ktmax; ++kt) {
    __syncthreads();
    const short* Kg = Kk + hb + (size_t)(kt * 64 + w * 16 + rl8) * HD + gch * 8;
    gll16(Kg, &Kls[(w * 16) * 64]);
    gll16(Kg + (size_t)8 * HD, &Kls[(w * 16 + 8) * 64]);
    const short* Vg = VT + hb + (size_t)(w * 16 + rl8) * S_LEN + kt * 64 + gch * 8;
    gll16(Vg, &Vls[(w * 16) * 64]);
    gll16(Vg + (size_t)8 * S_LEN, &Vls[(w * 16 + 8) * 64]);
    __syncthreads();
    bfrag kf[4][2];
    for (int nb = 0; nb < 4; ++nb)
      for (int kc = 0; kc < 2; ++kc)
        kf[nb][kc] = *reinterpret_cast<const bfrag*>(
            &Kls[(nb * 16 + lr) * 64 + (((kc * 4 + lg) ^ (lr & 7)) * 8)]);
    f32x4 sv[2][4];
    for (int mt = 0; mt < 2; ++mt)
      for (int nb = 0; nb < 4; ++nb) {
        f32x4 z = {0.f, 0.f, 0.f, 0.f};
        z = __builtin_amdgcn_mfma_f32_16x16x32_bf16(qf[mt][0], kf[nb][0], z, 0, 0, 0);
        sv[mt][nb] = __builtin_amdgcn_mfma_f32_16x16x32_bf16(qf[mt][1], kf[nb][1], z, 0, 0, 0);
      }
    if (kt * 64 + 63 > q0) {
      for (int mt = 0; mt < 2; ++mt)
        for (int nb = 0; nb < 4; ++nb)
          for (int i = 0; i < 4; ++i) {
            int colg = kt * 64 + nb * 16 + lr;
            int rowg = q0 + mt * 16 + lg * 4 + i;
            if (colg > rowg) sv[mt][nb][i] = -1e30f;
          }
    }
    for (int mt = 0; mt < 2; ++mt)
      for (int nb = 0; nb < 4; ++nb)
        for (int i = 0; i < 4; ++i)
          Pw[(mt * 16 + lg * 4 + i) * 72 + nb * 16 + lr] = f2bf_n(exp2f(sv[mt][nb][i]));
    bfrag vf[4][2];
    for (int nd = 0; nd < 4; ++nd)
      for (int kc = 0; kc < 2; ++kc)
        vf[nd][kc] = *reinterpret_cast<const bfrag*>(
            &Vls[(nd * 16 + lr) * 64 + (((kc * 4 + lg) ^ (lr & 7)) * 8)]);
    for (int mt = 0; mt < 2; ++mt) {
      bfrag pa0 = *reinterpret_cast<const bfrag*>(&Pw[(mt * 16 + lr) * 72 + lg * 8]);
      bfrag pa1 = *reinterpret_cast<const bfrag*>(&Pw[(mt * 16 + lr) * 72 + 32 + lg * 8]);
      for (int nd = 0; nd < 4; ++nd) {
        oacc[mt][nd] = __builtin_amdgcn_mfma_f32_16x16x32_bf16(pa0, vf[nd][0], oacc[mt][nd], 0, 0, 0);
        oacc[mt][nd] = __builtin_amdgcn_mfma_f32_16x16x32_bf16(pa1, vf[nd][1], oacc[mt][nd], 0, 0, 0);
      }
      osum[mt] = __builtin_amdgcn_mfma_f32_16x16x32_bf16(pa0, onesv, osum[mt], 0, 0, 0);
      osum[mt] = __builtin_amdgcn_mfma_f32_16x16x32_bf16(pa1, onesv, osum[mt], 0, 0, 0);
    }
  }

  for (int mt = 0; mt < 2; ++mt)
    for (int i = 0; i < 4; ++i) {
      int rowg = q0 + mt * 16 + lg * 4 + i;
      float inv = 1.0f / osum[mt][i];
      for (int nd = 0; nd < 4; ++nd)
        fwd[(size_t)(b * S_LEN + rowg) * DMODEL + h * HD + nd * 16 + lr] =
            f2bf(oacc[mt][nd][i] * inv);
    }
}

// ---------------- gate LN + sigmoid + fuse (sums 2 partials) ----------------
__global__ __launch_bounds__(256) void ln_gate_fuse_kernel(
    const float* __restrict__ g0p, const float* __restrict__ g1p,
    const float* __restrict__ gln_g, const float* __restrict__ gln_b,
    const short* __restrict__ fwd, const short* __restrict__ bwd,
    const float* __restrict__ bstr, short* __restrict__ fused) {
  __shared__ float red[8];
  const int row = blockIdx.x;
  const int tid = threadIdx.x;
  const int lane = tid & 63;
  const int w = tid >> 6;
  float4 x0 = *reinterpret_cast<const float4*>(g0p + (size_t)row * DMODEL + tid * 4);
  float4 x1 = *reinterpret_cast<const float4*>(g1p + (size_t)row * DMODEL + tid * 4);
  float xa[4] = {x0.x + x1.x, x0.y + x1.y, x0.z + x1.z, x0.w + x1.w};
  float s = xa[0] + xa[1] + xa[2] + xa[3];
  float ss = xa[0] * xa[0] + xa[1] * xa[1] + xa[2] * xa[2] + xa[3] * xa[3];
  for (int off = 1; off < 64; off <<= 1) {
    s += __shfl_xor(s, off);
    ss += __shfl_xor(ss, off);
  }
  if (lane == 0) { red[w] = s; red[4 + w] = ss; }
  __syncthreads();
  s = red[0] + red[1] + red[2] + red[3];
  ss = red[4] + red[5] + red[6] + red[7];
  const float mean = s * (1.f / DMODEL);
  const float var = ss * (1.f / DMODEL) - mean * mean;
  const float rstd = rsqrtf(var + 1e-5f);
  const float strength = 0.3f / (1.f + __expf(-bstr[0]));
  for (int e = 0; e < 4; ++e) {
    int idx = tid * 4 + e;
    float g = (xa[e] - mean) * rstd * gln_g[idx] + gln_b[idx];
    float gate = 1.f / (1.f + __expf(-g));
    float f = bf2f(fwd[(size_t)row * DMODEL + idx]) +
              strength * gate * bf2f(bwd[(size_t)row * DMODEL + idx]);
    fused[(size_t)row * DMODEL + idx] = f2bf(f);
  }
}

// ---------------- final residual LN (sums 2 partials) ----------------
__global__ __launch_bounds__(256) void final_ln_kernel(const float* __restrict__ x,
                                                       const float* __restrict__ o0p,
                                                       const float* __restrict__ o1p,
                                                       const float* __restrict__ ln_g,
                                                       const float* __restrict__ ln_b,
                                                       float* __restrict__ y) {
  __shared__ float red[8];
  const int row = blockIdx.x;
  const int tid = threadIdx.x;
  const int lane = tid & 63;
  const int w = tid >> 6;
  float4 xv = *reinterpret_cast<const float4*>(x + (size_t)row * DMODEL + tid * 4);
  float4 o0 = *reinterpret_cast<const float4*>(o0p + (size_t)row * DMODEL + tid * 4);
  float4 o1 = *reinterpret_cast<const float4*>(o1p + (size_t)row * DMODEL + tid * 4);
  float t[4] = {xv.x + o0.x + o1.x, xv.y + o0.y + o1.y,
                xv.z + o0.z + o1.z, xv.w + o0.w + o1.w};
  float s = t[0] + t[1] + t[2] + t[3];
  float ss = t[0] * t[0] + t[1] * t[1] + t[2] * t[2] + t[3] * t[3];
  for (int off = 1; off < 64; off <<= 1) {
    s += __shfl_xor(s, off);
    ss += __shfl_xor(ss, off);
  }
  if (lane == 0) { red[w] = s; red[4 + w] = ss; }
  __syncthreads();
  s = red[0] + red[1] + red[2] + red[3];
  ss = red[4] + red[5] + red[6] + red[7];
  const float mean = s * (1.f / DMODEL);
  const float var = ss * (1.f / DMODEL) - mean * mean;
  const float rstd = rsqrtf(var + 1e-5f);
  for (int e = 0; e < 4; ++e) {
    int idx = tid * 4 + e;
    y[(size_t)row * DMODEL + idx] = (t[e] - mean) * rstd * ln_g[idx] + ln_b[idx];
  }
}

extern "C" void kernel_launch(void* const* d_in, const int* in_sizes, int n_in,
                              void* d_out, int out_size, void* d_ws, size_t ws_size,
                              hipStream_t stream) {
  const float* x = (const float*)d_in[0];
  const float* fq_w = (const float*)d_in[1];
  const float* fq_b = (const float*)d_in[2];
  const float* fk_w = (const float*)d_in[3];
  const float* fk_b = (const float*)d_in[4];
  const float* fv_w = (const float*)d_in[5];
  const float* fv_b = (const float*)d_in[6];
  const float* bq_w = (const float*)d_in[7];
  const float* bq_b = (const float*)d_in[8];
  const float* bk_w = (const float*)d_in[9];
  const float* bk_b = (const float*)d_in[10];
  const float* bv_w = (const float*)d_in[11];
  const float* bv_b = (const float*)d_in[12];
  const float* gate_w = (const float*)d_in[13];
  const float* gate_b = (const float*)d_in[14];
  const float* gln_g = (const float*)d_in[15];
  const float* gln_b = (const float*)d_in[16];
  const float* bstr = (const float*)d_in[17];
  const float* out_w = (const float*)d_in[18];
  const float* out_b = (const float*)d_in[19];
  const float* ln_g = (const float*)d_in[20];
  const float* ln_b = (const float*)d_in[21];

  char* ws = (char*)d_ws;
  const size_t MB = 1u << 20;
  short* xb = (short*)(ws + 0);
  short* wT0 = (short*)(ws + 8 * MB);
  short* wT1 = (short*)(ws + 10 * MB);
  short* wT2 = (short*)(ws + 12 * MB);
  short* wT3 = (short*)(ws + 14 * MB);
  short* wT4 = (short*)(ws + 16 * MB);
  short* wT5 = (short*)(ws + 18 * MB);
  short* gwT = (short*)(ws + 20 * MB);
  short* owT = (short*)(ws + 24 * MB);
  short* qkv = (short*)(ws + 26 * MB);
  short* fwd = (short*)(ws + 0);
  short* bwdb = (short*)(ws + 8 * MB);
  float* G0 = (float*)(ws + 26 * MB);
  float* G1 = (float*)(ws + 42 * MB);
  short* fused = (short*)(ws + 58 * MB);
  float* O0 = (float*)(ws + 26 * MB);
  float* O1 = (float*)(ws + 42 * MB);

  prep_kernel<<<dim3(32, 64, 9), dim3(32, 8), 0, stream>>>(
      fq_w, fk_w, fv_w, bq_w, bk_w, bv_w, out_w, gate_w,
      wT0, wT1, wT2, wT3, wT4, wT5, owT, gwT, x, xb);

  gemm_qkv_kernel<<<dim3(48, 32), 256, 0, stream>>>(
      xb, 1024, 1024, wT0, wT1, wT2, wT3, wT4, wT5,
      fq_b, fk_b, fv_b, bq_b, bk_b, bv_b, qkv);

  attn_all_kernel<<<1056, 256, 0, stream>>>(
      qkv, qkv + (size_t)ELTS_PER, qkv + 2 * (size_t)ELTS_PER,
      qkv + 3 * (size_t)ELTS_PER, qkv + 4 * (size_t)ELTS_PER, qkv + 5 * (size_t)ELTS_PER,
      fwd, bwdb);

  gemm_ksplit_kernel<<<dim3(8, 32, 2), 256, 0, stream>>>(
      fwd, bwdb, 1024, gwT, 2048, 1024, gate_b, G0, G1);

  ln_gate_fuse_kernel<<<4096, 256, 0, stream>>>(G0, G1, gln_g, gln_b, fwd, bwdb, bstr, fused);

  gemm_ksplit_kernel<<<dim3(8, 32, 2), 256, 0, stream>>>(
      fused, fused + 512, 1024, owT, 1024, 512, out_b, O0, O1);

  final_ln_kernel<<<4096, 256, 0, stream>>>(x, O0, O1, ln_g, ln_b, (float*)d_out);
}